// Round 2
// baseline (215.679 us; speedup 1.0000x reference)
//
#include <hip/hip_runtime.h>
#include <hip/hip_bf16.h>

#define NV 100000
#define ND 64
#define NB 4096
#define NL 200
#define WST 72   // wbT row stride (bf16 elems): 64+8 pad keeps b128 reads low-conflict

typedef __bf16 bf16_t;
typedef __bf16 bf16x8 __attribute__((ext_vector_type(8)));
typedef __bf16 bf16x4 __attribute__((ext_vector_type(4)));
typedef float  f32x4  __attribute__((ext_vector_type(4)));

__global__ __launch_bounds__(256, 5)
void din_kernel1(const int* __restrict__ item_ids,
                 const int* __restrict__ history,
                 const int* __restrict__ hist_len,
                 const float* __restrict__ emb,
                 const float* __restrict__ aW1,
                 const float* __restrict__ ab1,
                 const float* __restrict__ aW2,
                 float* __restrict__ comb_ws)
{
    __shared__ __align__(16) bf16_t wbT[64 * WST];   // wbT[n][k] = W1a[k][n] + tgt[k]*W1c[k][n]
    __shared__ __align__(16) float scores[208];
    __shared__ float wts[208];
    __shared__ int   hidx[208];
    __shared__ float pp[4 * 64];
    __shared__ float tgt[64];
    __shared__ float cb[64];
    __shared__ float red[8];
    __shared__ float pooled[64];

    const int b    = blockIdx.x;
    const int tid  = threadIdx.x;
    const int item = item_ids[b];
    const int len  = hist_len[b];              // in [1, 200]
    const int wave = tid >> 6, lane = tid & 63;
    const int col  = lane & 15, quad = lane >> 4;

    if (tid < 64) tgt[tid] = emb[(long)item * ND + tid];   // f32 target row (for comb)

    // ---- phase 2: build Wb^T (bf16) + cb partials. All loads direct from global. ----
    {
        const int n4 = (tid & 15) * 4;    // 4 output cols
        const int kp = tid >> 4;          // 0..15 -> 4 k's
        f32x4 t4  = *(const f32x4*)(emb + (long)item * ND + kp * 4);
        f32x4 wa0 = *(const f32x4*)(aW1 + (kp * 4 + 0) * 64 + n4);
        f32x4 wa1 = *(const f32x4*)(aW1 + (kp * 4 + 1) * 64 + n4);
        f32x4 wa2 = *(const f32x4*)(aW1 + (kp * 4 + 2) * 64 + n4);
        f32x4 wa3 = *(const f32x4*)(aW1 + (kp * 4 + 3) * 64 + n4);
        f32x4 wb0 = *(const f32x4*)(aW1 + (64 + kp * 4 + 0) * 64 + n4);
        f32x4 wb1 = *(const f32x4*)(aW1 + (64 + kp * 4 + 1) * 64 + n4);
        f32x4 wb2 = *(const f32x4*)(aW1 + (64 + kp * 4 + 2) * 64 + n4);
        f32x4 wb3 = *(const f32x4*)(aW1 + (64 + kp * 4 + 3) * 64 + n4);
        f32x4 wc0 = *(const f32x4*)(aW1 + (128 + kp * 4 + 0) * 64 + n4);
        f32x4 wc1 = *(const f32x4*)(aW1 + (128 + kp * 4 + 1) * 64 + n4);
        f32x4 wc2 = *(const f32x4*)(aW1 + (128 + kp * 4 + 2) * 64 + n4);
        f32x4 wc3 = *(const f32x4*)(aW1 + (128 + kp * 4 + 3) * 64 + n4);

        f32x4 c4;
        #pragma unroll
        for (int j = 0; j < 4; ++j) {
            bf16x4 w;
            w[0] = (bf16_t)(wa0[j] + t4[0] * wc0[j]);
            w[1] = (bf16_t)(wa1[j] + t4[1] * wc1[j]);
            w[2] = (bf16_t)(wa2[j] + t4[2] * wc2[j]);
            w[3] = (bf16_t)(wa3[j] + t4[3] * wc3[j]);
            *(bf16x4*)&wbT[(n4 + j) * WST + kp * 4] = w;
            c4[j] = t4[0] * wb0[j] + t4[1] * wb1[j] + t4[2] * wb2[j] + t4[3] * wb3[j];
        }
        // reduce c4 over the 4 kp-subgroups within this wave (lane bits 4,5)
        #pragma unroll
        for (int j = 0; j < 4; ++j) {
            c4[j] += __shfl_xor(c4[j], 16, 64);
            c4[j] += __shfl_xor(c4[j], 32, 64);
        }
        if (lane < 16) *(f32x4*)&pp[wave * 64 + n4] = c4;
    }

    // ---- phase 3 tile-0 gather: issue BEFORE the barrier (independent of LDS) ----
    const int  l0   = wave * 16 + col;                 // mt0 = wave
    const int  lc0  = l0 < NL ? l0 : NL - 1;
    const int  idx0 = history[b * NL + lc0];
    const bool v0   = l0 < len;
    const float* s0 = emb + (long)idx0 * ND + quad * 8;
    f32x4 pa0 = *(const f32x4*)(s0);
    f32x4 pa1 = *(const f32x4*)(s0 + 4);
    f32x4 pa2 = *(const f32x4*)(s0 + 32);
    f32x4 pa3 = *(const f32x4*)(s0 + 36);

    __syncthreads();   // wbT + pp visible

    if (tid < 64) cb[tid] = ab1[tid] + pp[tid] + pp[64 + tid] + pp[128 + tid] + pp[192 + tid];

    // B-frags from LDS (reused across all m-tiles)
    bf16x8 bfrag[4][2];
    #pragma unroll
    for (int nt = 0; nt < 4; ++nt)
        #pragma unroll
        for (int kb = 0; kb < 2; ++kb)
            bfrag[nt][kb] = *(const bf16x8*)&wbT[(nt * 16 + col) * WST + kb * 32 + quad * 8];
    float a2vals[4];
    #pragma unroll
    for (int nt = 0; nt < 4; ++nt) a2vals[nt] = aW2[nt * 16 + col];

    __syncthreads();   // cb visible
    float cvals[4];
    #pragma unroll
    for (int nt = 0; nt < 4; ++nt) cvals[nt] = cb[nt * 16 + col];

    // ---- phase 3: scores via MFMA, A-frags straight from global ----
    auto do_tile = [&](int mt, f32x4 a0, f32x4 a1, f32x4 a2, f32x4 a3, bool valid) {
        bf16x8 af0, af1;
        #pragma unroll
        for (int i = 0; i < 4; ++i) {
            af0[i]     = (bf16_t)a0[i];
            af0[i + 4] = (bf16_t)a1[i];
            af1[i]     = (bf16_t)a2[i];
            af1[i + 4] = (bf16_t)a3[i];
        }
        if (!valid) { af0 = (bf16x8)(bf16_t)0.f; af1 = (bf16x8)(bf16_t)0.f; }
        float sc[4] = {0.f, 0.f, 0.f, 0.f};
        #pragma unroll
        for (int nt = 0; nt < 4; ++nt) {
            f32x4 acc = {0.f, 0.f, 0.f, 0.f};
            acc = __builtin_amdgcn_mfma_f32_16x16x32_bf16(af0, bfrag[nt][0], acc, 0, 0, 0);
            acc = __builtin_amdgcn_mfma_f32_16x16x32_bf16(af1, bfrag[nt][1], acc, 0, 0, 0);
            #pragma unroll
            for (int i = 0; i < 4; ++i) {
                float h = acc[i] + cvals[nt];
                h = h > 0.f ? h : 0.f;
                sc[i] += h * a2vals[nt];
            }
        }
        #pragma unroll
        for (int off = 1; off < 16; off <<= 1)
            #pragma unroll
            for (int i = 0; i < 4; ++i) sc[i] += __shfl_xor(sc[i], off, 64);
        if (col == 0) {
            f32x4 outv = {sc[0], sc[1], sc[2], sc[3]};   // rows quad*4+0..3 of this tile
            *(f32x4*)&scores[mt * 16 + quad * 4] = outv;
        }
    };

    if (quad == 0 && l0 < NL) hidx[l0] = idx0;
    do_tile(wave, pa0, pa1, pa2, pa3, v0);

    for (int mt = wave + 4; mt < 13; mt += 4) {
        const int  l    = mt * 16 + col;
        const int  lc   = l < NL ? l : NL - 1;
        const int  idxv = history[b * NL + lc];
        const bool vv   = l < len;
        const float* sp = emb + (long)idxv * ND + quad * 8;
        f32x4 a0 = *(const f32x4*)(sp);
        f32x4 a1 = *(const f32x4*)(sp + 4);
        f32x4 a2 = *(const f32x4*)(sp + 32);
        f32x4 a3 = *(const f32x4*)(sp + 36);
        if (quad == 0 && l < NL) hidx[l] = idxv;
        do_tile(mt, a0, a1, a2, a3, vv);
    }
    __syncthreads();   // scores + hidx complete

    // ---- phase 4: softmax over exactly L=200 ----
    {
        float s = (tid < NL) ? scores[tid] : -1e30f;
        float m = s;
        #pragma unroll
        for (int off = 32; off > 0; off >>= 1) m = fmaxf(m, __shfl_xor(m, off, 64));
        if (lane == 0) red[wave] = m;
        __syncthreads();
        m = fmaxf(fmaxf(red[0], red[1]), fmaxf(red[2], red[3]));
        float e = (tid < NL) ? __expf(s - m) : 0.f;
        float ssum = e;
        #pragma unroll
        for (int off = 32; off > 0; off >>= 1) ssum += __shfl_xor(ssum, off, 64);
        if (lane == 0) red[4 + wave] = ssum;
        __syncthreads();
        float tot = red[4] + red[5] + red[6] + red[7];
        if (tid < NL) wts[tid] = e / tot;
    }
    __syncthreads();

    // ---- phase 5: pooled = sum_l w_l * emb[idx_l]  (rows are L2-hot; coalesced 256B) ----
    {
        float acc = 0.f;
        for (int l = wave; l < NL; l += 4) {
            float wl = (l < len) ? wts[l] : 0.f;
            acc += wl * emb[(long)hidx[l] * ND + lane];
        }
        pp[wave * 64 + lane] = acc;
    }
    __syncthreads();
    if (tid < 64) pooled[tid] = pp[tid] + pp[64 + tid] + pp[128 + tid] + pp[192 + tid];
    __syncthreads();

    // ---- phase 6: comb = [tgt, pooled, pooled - tgt] ----
    if (tid < 192) {
        float v;
        if (tid < 64)       v = tgt[tid];
        else if (tid < 128) v = pooled[tid - 64];
        else                v = pooled[tid - 128] - tgt[tid - 128];
        comb_ws[(long)b * 192 + tid] = v;
    }
}

// one wave per batch row; 4 rows per block; 1024 blocks -> 4 blocks/CU
__global__ __launch_bounds__(256)
void din_kernel2(const float* __restrict__ comb,
                 const float* __restrict__ fW1, const float* __restrict__ fb1,
                 const float* __restrict__ fW2, const float* __restrict__ fb2,
                 const float* __restrict__ fW3, const float* __restrict__ fb3,
                 float* __restrict__ out)
{
    __shared__ float z1s[4 * 128];
    const int tid  = threadIdx.x;
    const int wave = tid >> 6, lane = tid & 63;
    const int row  = blockIdx.x * 4 + wave;

    const float* crow = comb + (long)row * 192;
    float acc0 = fb1[lane], acc1 = fb1[64 + lane];
    #pragma unroll 4
    for (int i4 = 0; i4 < 48; ++i4) {
        f32x4 cm = *(const f32x4*)(crow + i4 * 4);
        #pragma unroll
        for (int u = 0; u < 4; ++u) {
            const int i = i4 * 4 + u;
            acc0 += cm[u] * fW1[i * 128 + lane];
            acc1 += cm[u] * fW1[i * 128 + 64 + lane];
        }
    }
    z1s[wave * 128 + lane]      = fmaxf(acc0, 0.f);
    z1s[wave * 128 + 64 + lane] = fmaxf(acc1, 0.f);
    __syncthreads();

    float a2 = fb2[lane];
    #pragma unroll 4
    for (int i = 0; i < 128; ++i) a2 += z1s[wave * 128 + i] * fW2[i * 64 + lane];
    float z2v = fmaxf(a2, 0.f);

    float s = z2v * fW3[lane];
    #pragma unroll
    for (int off = 1; off < 64; off <<= 1) s += __shfl_xor(s, off, 64);
    if (lane == 0) out[row] = 1.f / (1.f + __expf(-(s + fb3[0])));
}

extern "C" void kernel_launch(void* const* d_in, const int* in_sizes, int n_in,
                              void* d_out, int out_size, void* d_ws, size_t ws_size,
                              hipStream_t stream) {
    const int*   item_ids = (const int*)d_in[0];
    const int*   history  = (const int*)d_in[1];
    const int*   hist_len = (const int*)d_in[2];
    const float* emb      = (const float*)d_in[3];
    const float* aW1      = (const float*)d_in[4];
    const float* ab1      = (const float*)d_in[5];
    const float* aW2      = (const float*)d_in[6];
    // d_in[7] = ab2: softmax shift-invariance -> exactly cancels, unused
    const float* fW1      = (const float*)d_in[8];
    const float* fb1      = (const float*)d_in[9];
    const float* fW2      = (const float*)d_in[10];
    const float* fb2      = (const float*)d_in[11];
    const float* fW3      = (const float*)d_in[12];
    const float* fb3      = (const float*)d_in[13];

    float* comb = (float*)d_ws;   // 4096*192*4 = 3.1 MB scratch

    din_kernel1<<<NB, 256, 0, stream>>>(item_ids, history, hist_len, emb,
                                        aW1, ab1, aW2, comb);
    din_kernel2<<<NB / 4, 256, 0, stream>>>(comb, fW1, fb1, fW2, fb2, fW3, fb3,
                                            (float*)d_out);
}

// Round 3
// 166.231 us; speedup vs baseline: 1.2975x; 1.2975x over previous
//
#include <hip/hip_runtime.h>
#include <hip/hip_bf16.h>

#define NV 100000
#define ND 64
#define NB 4096
#define NL 200
#define HST 72   // histA row stride in bf16 elems (144 B = 9*16 -> b128-aligned, banks spread)

typedef __bf16 bf16_t;
typedef __bf16 bf16x8 __attribute__((ext_vector_type(8)));
typedef float  f32x4  __attribute__((ext_vector_type(4)));

__global__ __launch_bounds__(256, 5)
void din_kernel1(const int* __restrict__ item_ids,
                 const int* __restrict__ history,
                 const int* __restrict__ hist_len,
                 const float* __restrict__ emb,
                 const float* __restrict__ aW1,
                 const float* __restrict__ ab1,
                 const float* __restrict__ aW2,
                 float* __restrict__ comb_ws)
{
    // LDS budget: 29952 + 832 + 1024 + 256 + 256 + 256 + 32 = 32608 -> rounds to 32 KB -> 5 blocks/CU
    __shared__ __align__(16) bf16_t histA[208 * HST];
    __shared__ __align__(16) float sc_w[208];      // scores, then softmax weights in-place
    __shared__ float pp[256];
    __shared__ float tgt[64];
    __shared__ float cb[64];
    __shared__ float pooled[64];
    __shared__ float red[8];

    const int b    = blockIdx.x;
    const int tid  = threadIdx.x;
    const int item = item_ids[b];
    const int len  = hist_len[b];                  // [1, 200]
    const int wave = tid >> 6, lane = tid & 63;
    const int col  = lane & 15, quad = lane >> 4;

    if (tid < 64) tgt[tid] = emb[(long)item * ND + tid];

    // ---- phase 1: gather history -> bf16 LDS (full 256B rows, coalesced, ONE read/row) ----
    {
        const int p     = tid & 3;     // quarter row: 16 floats
        const int lbase = tid >> 2;    // 64 rows per pass
        int  idxs[4];
        bool vs[4];
        #pragma unroll
        for (int pass = 0; pass < 4; ++pass) {
            int l  = pass * 64 + lbase;
            int lc = l < NL ? l : NL - 1;
            idxs[pass] = history[b * NL + lc];
            vs[pass]   = l < len;
        }
        #pragma unroll
        for (int g = 0; g < 2; ++g) {      // two groups of two passes: 8 outstanding 16B loads
            f32x4 r[2][4];
            #pragma unroll
            for (int q = 0; q < 2; ++q) {
                int pass = g * 2 + q;
                int l = pass * 64 + lbase;
                if (l < 208 && vs[pass]) {
                    const float* src = emb + (long)idxs[pass] * ND + p * 16;
                    r[q][0] = *(const f32x4*)(src);
                    r[q][1] = *(const f32x4*)(src + 4);
                    r[q][2] = *(const f32x4*)(src + 8);
                    r[q][3] = *(const f32x4*)(src + 12);
                }
            }
            #pragma unroll
            for (int q = 0; q < 2; ++q) {
                int pass = g * 2 + q;
                int l = pass * 64 + lbase;
                if (l < 208) {
                    bf16x8 o0 = (bf16x8)(bf16_t)0.f, o1 = (bf16x8)(bf16_t)0.f;
                    if (vs[pass]) {
                        #pragma unroll
                        for (int i = 0; i < 4; ++i) {
                            o0[i]     = (bf16_t)r[q][0][i];
                            o0[i + 4] = (bf16_t)r[q][1][i];
                            o1[i]     = (bf16_t)r[q][2][i];
                            o1[i + 4] = (bf16_t)r[q][3][i];
                        }
                    }
                    bf16_t* dst = &histA[l * HST + p * 16];
                    *(bf16x8*)(dst)     = o0;
                    *(bf16x8*)(dst + 8) = o1;
                }
            }
        }
    }

    // ---- phase 2a: cb partials (tgt-term of middle 64 rows of aW1), global loads only ----
    {
        const int n4 = (tid & 15) * 4;
        const int kp = tid >> 4;                   // 0..15 -> k in [kp*4, kp*4+4)
        f32x4 t4  = *(const f32x4*)(emb + (long)item * ND + kp * 4);
        f32x4 wb0 = *(const f32x4*)(aW1 + (64 + kp * 4 + 0) * 64 + n4);
        f32x4 wb1 = *(const f32x4*)(aW1 + (64 + kp * 4 + 1) * 64 + n4);
        f32x4 wb2 = *(const f32x4*)(aW1 + (64 + kp * 4 + 2) * 64 + n4);
        f32x4 wb3 = *(const f32x4*)(aW1 + (64 + kp * 4 + 3) * 64 + n4);
        f32x4 c4;
        #pragma unroll
        for (int j = 0; j < 4; ++j)
            c4[j] = t4[0] * wb0[j] + t4[1] * wb1[j] + t4[2] * wb2[j] + t4[3] * wb3[j];
        #pragma unroll
        for (int j = 0; j < 4; ++j) {
            c4[j] += __shfl_xor(c4[j], 16, 64);
            c4[j] += __shfl_xor(c4[j], 32, 64);
        }
        if (lane < 16) *(f32x4*)&pp[wave * 64 + n4] = c4;
    }

    __syncthreads();   // histA + pp + tgt visible

    if (tid < 64) cb[tid] = ab1[tid] + pp[tid] + pp[64 + tid] + pp[128 + tid] + pp[192 + tid];

    // ---- B-frags per lane, straight from global (coalesced 64B across col, L2-hot) ----
    bf16x8 bfrag[4][2];
    #pragma unroll
    for (int kb = 0; kb < 2; ++kb) {
        f32x4 t0 = *(const f32x4*)&tgt[kb * 32 + quad * 8];
        f32x4 t1 = *(const f32x4*)&tgt[kb * 32 + quad * 8 + 4];
        #pragma unroll
        for (int nt = 0; nt < 4; ++nt) {
            const int n = nt * 16 + col;
            const float* pa = aW1 + (long)(kb * 32 + quad * 8) * 64 + n;
            const float* pc = pa + 128 * 64;
            float wa[8], wc[8];
            #pragma unroll
            for (int j = 0; j < 8; ++j) { wa[j] = pa[j * 64]; wc[j] = pc[j * 64]; }
            bf16x8 w;
            #pragma unroll
            for (int j = 0; j < 8; ++j) {
                float tk = (j < 4) ? t0[j] : t1[j - 4];
                w[j] = (bf16_t)(wa[j] + tk * wc[j]);
            }
            bfrag[nt][kb] = w;
        }
    }
    float a2vals[4];
    #pragma unroll
    for (int nt = 0; nt < 4; ++nt) a2vals[nt] = aW2[nt * 16 + col];

    __syncthreads();   // cb visible
    float cvals[4];
    #pragma unroll
    for (int nt = 0; nt < 4; ++nt) cvals[nt] = cb[nt * 16 + col];

    // ---- phase 3: scores via MFMA, A-frags from LDS (b128, stride-72 conflict-free) ----
    for (int mt = wave; mt < 13; mt += 4) {
        const bf16_t* arow = &histA[(mt * 16 + col) * HST + quad * 8];
        bf16x8 af0 = *(const bf16x8*)(arow);
        bf16x8 af1 = *(const bf16x8*)(arow + 32);
        float sc[4] = {0.f, 0.f, 0.f, 0.f};
        #pragma unroll
        for (int nt = 0; nt < 4; ++nt) {
            f32x4 acc = {0.f, 0.f, 0.f, 0.f};
            acc = __builtin_amdgcn_mfma_f32_16x16x32_bf16(af0, bfrag[nt][0], acc, 0, 0, 0);
            acc = __builtin_amdgcn_mfma_f32_16x16x32_bf16(af1, bfrag[nt][1], acc, 0, 0, 0);
            #pragma unroll
            for (int i = 0; i < 4; ++i) {
                float h = acc[i] + cvals[nt];
                h = h > 0.f ? h : 0.f;
                sc[i] += h * a2vals[nt];
            }
        }
        #pragma unroll
        for (int off = 1; off < 16; off <<= 1)
            #pragma unroll
            for (int i = 0; i < 4; ++i) sc[i] += __shfl_xor(sc[i], off, 64);
        if (col == 0) {
            f32x4 outv = {sc[0], sc[1], sc[2], sc[3]};   // rows quad*4+0..3
            *(f32x4*)&sc_w[mt * 16 + quad * 4] = outv;
        }
    }
    __syncthreads();

    // ---- phase 4: softmax over exactly L=200 (weights written in-place) ----
    {
        float s = (tid < NL) ? sc_w[tid] : -1e30f;
        float m = s;
        #pragma unroll
        for (int off = 32; off > 0; off >>= 1) m = fmaxf(m, __shfl_xor(m, off, 64));
        if (lane == 0) red[wave] = m;
        __syncthreads();
        m = fmaxf(fmaxf(red[0], red[1]), fmaxf(red[2], red[3]));
        float e = (tid < NL) ? __expf(s - m) : 0.f;
        float ssum = e;
        #pragma unroll
        for (int off = 32; off > 0; off >>= 1) ssum += __shfl_xor(ssum, off, 64);
        if (lane == 0) red[4 + wave] = ssum;
        __syncthreads();
        float tot = red[4] + red[5] + red[6] + red[7];
        if (tid < NL) sc_w[tid] = e / tot;    // own element only: no cross-thread hazard
    }
    __syncthreads();

    // ---- phase 5: pooled from LDS histA (rows >= len are already zero) ----
    {
        float acc = 0.f;
        for (int l = wave; l < NL; l += 4)
            acc += sc_w[l] * (float)histA[l * HST + lane];
        pp[wave * 64 + lane] = acc;
    }
    __syncthreads();
    if (tid < 64) pooled[tid] = pp[tid] + pp[64 + tid] + pp[128 + tid] + pp[192 + tid];
    __syncthreads();

    // ---- phase 6: comb = [tgt, pooled, pooled - tgt] ----
    if (tid < 192) {
        float v;
        if (tid < 64)       v = tgt[tid];
        else if (tid < 128) v = pooled[tid - 64];
        else                v = pooled[tid - 128] - tgt[tid - 128];
        comb_ws[(long)b * 192 + tid] = v;
    }
}

// 1024 blocks x 256 thr: 4 rows/block, thread owns one z1 col for 2 rows
__global__ __launch_bounds__(256)
void din_kernel2(const float* __restrict__ comb,
                 const float* __restrict__ fW1, const float* __restrict__ fb1,
                 const float* __restrict__ fW2, const float* __restrict__ fb2,
                 const float* __restrict__ fW3, const float* __restrict__ fb3,
                 float* __restrict__ out)
{
    __shared__ float combs[4 * 192];
    __shared__ float z1s[4 * 128];
    const int tid = threadIdx.x;
    const int rb  = blockIdx.x * 4;

    for (int i = tid; i < 4 * 192; i += 256) combs[i] = comb[(long)rb * 192 + i];
    __syncthreads();

    {
        const int j  = tid & 127;
        const int r0 = (tid >> 7) * 2, r1 = r0 + 1;
        float a0 = fb1[j], a1 = a0;
        #pragma unroll 4
        for (int i = 0; i < 192; ++i) {
            float w = fW1[i * 128 + j];
            a0 += combs[r0 * 192 + i] * w;   // LDS broadcast
            a1 += combs[r1 * 192 + i] * w;
        }
        z1s[r0 * 128 + j] = fmaxf(a0, 0.f);
        z1s[r1 * 128 + j] = fmaxf(a1, 0.f);
    }
    __syncthreads();

    {
        const int j2 = tid & 63;
        const int r2 = tid >> 6;
        float acc = fb2[j2];
        #pragma unroll 4
        for (int i = 0; i < 128; ++i)
            acc += z1s[r2 * 128 + i] * fW2[i * 64 + j2];
        float s = fmaxf(acc, 0.f) * fW3[j2];
        #pragma unroll
        for (int off = 1; off < 64; off <<= 1) s += __shfl_xor(s, off, 64);
        if (j2 == 0) out[rb + r2] = 1.f / (1.f + __expf(-(s + fb3[0])));
    }
}

extern "C" void kernel_launch(void* const* d_in, const int* in_sizes, int n_in,
                              void* d_out, int out_size, void* d_ws, size_t ws_size,
                              hipStream_t stream) {
    const int*   item_ids = (const int*)d_in[0];
    const int*   history  = (const int*)d_in[1];
    const int*   hist_len = (const int*)d_in[2];
    const float* emb      = (const float*)d_in[3];
    const float* aW1      = (const float*)d_in[4];
    const float* ab1      = (const float*)d_in[5];
    const float* aW2      = (const float*)d_in[6];
    // d_in[7] = ab2: softmax shift-invariance -> exactly cancels, unused
    const float* fW1      = (const float*)d_in[8];
    const float* fb1      = (const float*)d_in[9];
    const float* fW2      = (const float*)d_in[10];
    const float* fb2      = (const float*)d_in[11];
    const float* fW3      = (const float*)d_in[12];
    const float* fb3      = (const float*)d_in[13];

    float* comb = (float*)d_ws;   // 4096*192*4 = 3.1 MB scratch

    din_kernel1<<<NB, 256, 0, stream>>>(item_ids, history, hist_len, emb,
                                        aW1, ab1, aW2, comb);
    din_kernel2<<<NB / 4, 256, 0, stream>>>(comb, fW1, fb1, fW2, fb2, fW3, fb3,
                                            (float*)d_out);
}